// Round 1
// baseline (3285.780 us; speedup 1.0000x reference)
//
#include <hip/hip_runtime.h>
#include <hip/hip_bf16.h>

#define CAP 64   // max nnz per row/col of A (mean ~13, binomial(400,0.03)+diag)

// ---------------------------------------------------------------------------
// Kernel 1: build sparse row/col lists of A, AW=A*W1 values (CSC), and W2^T.
// grid: 400 blocks x 64 threads (1 wave); block m handles row m and col m.
// ---------------------------------------------------------------------------
__global__ __launch_bounds__(64) void build_sparse(
    const float* __restrict__ A, const float* __restrict__ W1,
    const float* __restrict__ W2,
    int* __restrict__ row_cnt, int* __restrict__ row_idx,
    int* __restrict__ col_cnt, int* __restrict__ col_idx,
    float* __restrict__ col_val, float* __restrict__ W2T)
{
    int m = blockIdx.x, lane = threadIdx.x;
    // W2 is (64,400); W2T[j][f] = W2[f][j]
    W2T[m * 64 + lane] = W2[lane * 400 + m];

    // row scan: j's with A[m,j] != 0 (attention mask)
    int base = 0;
    for (int c = 0; c < 400; c += 64) {
        int n = c + lane;
        float v = (n < 400) ? A[m * 400 + n] : 0.f;
        unsigned long long mk = __ballot(v != 0.f);
        int pre = __popcll(mk & ((1ull << lane) - 1ull));
        if (v != 0.f && base + pre < CAP) row_idx[m * CAP + base + pre] = n;
        base += __popcll(mk);
    }
    if (lane == 0) row_cnt[m] = base < CAP ? base : CAP;

    // col scan: n's with A[n,m] != 0, value AW[n,m] = A[n,m]*W1[n,m]
    base = 0;
    for (int c = 0; c < 400; c += 64) {
        int n = c + lane;
        float v = (n < 400) ? A[n * 400 + m] : 0.f;
        unsigned long long mk = __ballot(v != 0.f);
        int pre = __popcll(mk & ((1ull << lane) - 1ull));
        if (v != 0.f && base + pre < CAP) {
            col_idx[m * CAP + base + pre] = n;
            col_val[m * CAP + base + pre] = v * W1[n * 400 + m];
        }
        base += __popcll(mk);
    }
    if (lane == 0) col_cnt[m] = base < CAP ? base : CAP;
}

// ---------------------------------------------------------------------------
// Kernel 2: DynamicGC -> y (B,T,N,64). One block per (b,t), 4 waves, each wave
// processes rows m = w, w+4, ... independently (no barriers; cross-lane via
// shuffles only). Exploits sparsity of A for feat / dense / attn / nodef.
// ---------------------------------------------------------------------------
__global__ __launch_bounds__(256) void dgc_kernel(
    const float* __restrict__ x, const float* __restrict__ W2T,
    const float* __restrict__ W3, const float* __restrict__ b1,
    const float* __restrict__ b2,
    const int* __restrict__ row_cnt, const int* __restrict__ row_idx,
    const int* __restrict__ col_cnt, const int* __restrict__ col_idx,
    const float* __restrict__ col_val,
    float* __restrict__ y)
{
    int bt = blockIdx.x;
    const float* xs = x + (size_t)bt * 25600;
    float* ys = y + (size_t)bt * 25600;
    int tid = threadIdx.x, lane = tid & 63, w = tid >> 6;

    // W3 column u=lane in registers (64 VGPRs)
    float w3r[64];
#pragma unroll
    for (int f = 0; f < 64; ++f) w3r[f] = W3[f * 64 + lane];
    float b2v = b2[lane];

    for (int m = w; m < 400; m += 4) {
        // ---- feat[m, f=lane] = sum_n AW[n,m] * x[n,f]  (CSC col m) ----
        int cc = col_cnt[m];
        float feat = 0.f;
        for (int l = 0; l < cc; ++l) {
            int n = col_idx[m * CAP + l];
            float wv = col_val[m * CAP + l];
            feat += wv * xs[(size_t)n * 64 + lane];
        }
        // ---- dense[m, j_lane] for edges of row m, masked softmax ----
        int rc = row_cnt[m];                    // >= 1 (self loop)
        int lcl = lane < rc - 1 ? lane : rc - 1; // clamp so loads are safe
        int jj = row_idx[m * CAP + lcl];
        float d = b1[jj];
        const float4* w2r = (const float4*)(W2T + (size_t)jj * 64);
#pragma unroll
        for (int q = 0; q < 16; ++q) {
            float4 wv = w2r[q];
            d += __shfl(feat, 4 * q + 0) * wv.x + __shfl(feat, 4 * q + 1) * wv.y +
                 __shfl(feat, 4 * q + 2) * wv.z + __shfl(feat, 4 * q + 3) * wv.w;
        }
        float dv = (lane < rc) ? d : -1e30f;
        float mx = dv;
#pragma unroll
        for (int off = 32; off; off >>= 1) mx = fmaxf(mx, __shfl_xor(mx, off));
        float e = (lane < rc) ? __expf(dv - mx) : 0.f;
        float s = e;
#pragma unroll
        for (int off = 32; off; off >>= 1) s += __shfl_xor(s, off);
        float aval = e / s;
        // ---- nodef[m, f=lane] = sum_j attn[m,j] * x[j,f] ----
        float nf = 0.f;
        for (int l = 0; l < rc; ++l) {
            float av = __shfl(aval, l);
            int jv = __shfl(jj, l);
            nf += av * xs[(size_t)jv * 64 + lane];
        }
        // ---- y[m, u=lane] = nodef . W3[:,u] + b2[u] ----
        float yv = b2v;
#pragma unroll
        for (int f = 0; f < 64; ++f) yv += __shfl(nf, f) * w3r[f];
        ys[(size_t)m * 64 + lane] = yv;
    }
}

// ---------------------------------------------------------------------------
// Kernel 3: r1[bt,f] = sum_n y[bt,n,f]*taW1[n];  rhs[bt,n] = sum_f y*taW3[f]
// ---------------------------------------------------------------------------
__global__ __launch_bounds__(256) void ta_r1_rhs(
    const float* __restrict__ y, const float* __restrict__ taW1,
    const float* __restrict__ taW3, float* __restrict__ r1,
    float* __restrict__ rhs)
{
    int bt = blockIdx.x;
    const float* ys = y + (size_t)bt * 25600;
    int tid = threadIdx.x, lane = tid & 63, w = tid >> 6;
    __shared__ __align__(16) float part[4][64];
    __shared__ __align__(16) float w3s[64];
    if (tid < 64) w3s[tid] = taW3[tid];
    float acc = 0.f;
    for (int n = w * 100; n < w * 100 + 100; ++n)
        acc += taW1[n] * ys[(size_t)n * 64 + lane];
    part[w][lane] = acc;
    __syncthreads();
    if (w == 0)
        r1[bt * 64 + lane] = part[0][lane] + part[1][lane] + part[2][lane] + part[3][lane];
    for (int n = tid; n < 400; n += 256) {
        const float4* yr = (const float4*)(ys + (size_t)n * 64);
        float a = 0.f;
#pragma unroll
        for (int q = 0; q < 16; ++q) {
            float4 v = yr[q];
            float4 wv = ((const float4*)w3s)[q];
            a += v.x * wv.x + v.y * wv.y + v.z * wv.z + v.w * wv.w;
        }
        rhs[bt * 400 + n] = a;
    }
}

// ---------------------------------------------------------------------------
// Kernel 4: lhs[bt,n] = sum_f r1[bt,f] * taW2[f,n]
// ---------------------------------------------------------------------------
__global__ __launch_bounds__(256) void ta_lhs(
    const float* __restrict__ r1, const float* __restrict__ taW2,
    float* __restrict__ lhs)
{
    int bt = blockIdx.x, tid = threadIdx.x;
    __shared__ float r1s[64];
    if (tid < 64) r1s[tid] = r1[bt * 64 + tid];
    __syncthreads();
    for (int n = tid; n < 400; n += 256) {
        float acc = 0.f;
#pragma unroll 8
        for (int f = 0; f < 64; ++f) acc += r1s[f] * taW2[f * 400 + n];
        lhs[bt * 400 + n] = acc;
    }
}

// ---------------------------------------------------------------------------
// Kernel 5: S[b,k,l] = sigmoid( lhs[b,k,:].rhs[b,l,:] + be[k,l] )
// grid (15, 8): blockIdx.x = k-chunk of 4, blockIdx.y = b
// ---------------------------------------------------------------------------
__global__ __launch_bounds__(256) void ta_product(
    const float* __restrict__ lhs, const float* __restrict__ rhs,
    const float* __restrict__ be, float* __restrict__ S)
{
    int kc = blockIdx.x, b = blockIdx.y, tid = threadIdx.x;
    if (tid >= 240) return;
    int k = kc * 4 + tid / 60;
    int l = tid % 60;
    const float4* lr = (const float4*)(lhs + (size_t)(b * 60 + k) * 400);
    const float4* rr = (const float4*)(rhs + (size_t)(b * 60 + l) * 400);
    float acc = 0.f;
    for (int q = 0; q < 100; ++q) {
        float4 a = lr[q], c = rr[q];
        acc += a.x * c.x + a.y * c.y + a.z * c.z + a.w * c.w;
    }
    float v = acc + be[k * 60 + l];
    S[b * 3600 + k * 60 + l] = 1.f / (1.f + __expf(-v));
}

// ---------------------------------------------------------------------------
// Kernel 6: E[b,j,l] = sum_k Ve[j,k]*S[b,k,l]; ker = softmax over j.
// grid 8 blocks (per b).
// ---------------------------------------------------------------------------
__global__ __launch_bounds__(256) void ta_softmax(
    const float* __restrict__ S, const float* __restrict__ Ve,
    float* __restrict__ ker)
{
    int b = blockIdx.x, tid = threadIdx.x;
    __shared__ float Ss[3600];
    __shared__ float Emat[3600];
    for (int i = tid; i < 3600; i += 256) Ss[i] = S[b * 3600 + i];
    __syncthreads();
    for (int p = tid; p < 3600; p += 256) {
        int j = p / 60, l = p % 60;
        float acc = 0.f;
        for (int k = 0; k < 60; ++k) acc += Ve[j * 60 + k] * Ss[k * 60 + l];
        Emat[p] = acc;
    }
    __syncthreads();
    for (int l = tid; l < 60; l += 256) {
        float mx = -1e30f;
        for (int j = 0; j < 60; ++j) mx = fmaxf(mx, Emat[j * 60 + l]);
        float s = 0.f;
        for (int j = 0; j < 60; ++j) s += __expf(Emat[j * 60 + l] - mx);
        float inv = 1.f / s;
        for (int j = 0; j < 60; ++j)
            ker[b * 3600 + j * 60 + l] = __expf(Emat[j * 60 + l] - mx) * inv;
    }
}

// ---------------------------------------------------------------------------
// Kernel 7: fused time-mix (ta_out) + both temporal convs + softplus.
// One block per (n, b). In LDS: zero-padded input [71 rows][128 ch]
// (ch 0..63 = ta_out, ch 64..127 = x). SAME pad: lo=5, hi=6.
// out[b,t,n,u] = softplus( sum_dt sum_ci In[t+dt][ci]*K[dt,ci,u] + tb[u]+rb[u] )
// ---------------------------------------------------------------------------
__global__ __launch_bounds__(256) void fused_conv(
    const float* __restrict__ y, const float* __restrict__ ker,
    const float* __restrict__ x,
    const float* __restrict__ tk, const float* __restrict__ tb,
    const float* __restrict__ rk, const float* __restrict__ rb,
    float* __restrict__ out)
{
    int n = blockIdx.x, b = blockIdx.y;
    int tid = threadIdx.x, u = tid & 63, tg = tid >> 6;
    __shared__ __align__(16) float In[71 * 128];   // 36352 B
    __shared__ __align__(16) float buf[4096];      // 16384 B
    // zero-init padded input
    for (int i = tid; i < 71 * 128; i += 256) In[i] = 0.f;
    __syncthreads();
    // stage x into channels 64..127, rows 5..64
    for (int i = tid; i < 3840; i += 256) {
        int t = i >> 6, uu = i & 63;
        In[(t + 5) * 128 + 64 + uu] = x[((size_t)(b * 60 + t) * 400 + n) * 64 + uu];
    }
    // time-mix: ta_out[t',u] = sum_s ker[b,s,t'] * y[b,s,n,u], in 2 halves of s
    float acc[15];
#pragma unroll
    for (int i = 0; i < 15; ++i) acc[i] = 0.f;
    for (int half = 0; half < 2; ++half) {
        int s0 = half * 30;
        __syncthreads();
        for (int i = tid; i < 1920; i += 256) {
            int s = i >> 6, uu = i & 63;
            buf[i] = y[((size_t)(b * 60 + s0 + s) * 400 + n) * 64 + uu];
        }
        for (int i = tid; i < 1800; i += 256)
            buf[1920 + i] = ker[b * 3600 + (s0 + i / 60) * 60 + (i % 60)];
        __syncthreads();
        for (int s = 0; s < 30; ++s) {
            float yv = buf[s * 64 + u];
#pragma unroll
            for (int i = 0; i < 15; ++i)
                acc[i] += buf[1920 + s * 60 + tg * 15 + i] * yv;
        }
    }
    // write ta_out into channels 0..63 (dt-loop's first barrier orders this
    // before any cross-thread read)
#pragma unroll
    for (int i = 0; i < 15; ++i) In[(tg * 15 + i + 5) * 128 + u] = acc[i];

    float o[15];
    float bias = tb[u] + rb[u];
#pragma unroll
    for (int i = 0; i < 15; ++i) o[i] = bias;

    for (int dt = 0; dt < 12; ++dt) {
        for (int half = 0; half < 2; ++half) {
            __syncthreads();
            const float* K = (half == 0) ? tk : rk;  // (12,1,64,64) HWIO
            for (int i = tid; i < 4096; i += 256) buf[i] = K[dt * 4096 + i];
            __syncthreads();
            int cbase = half * 64;
            for (int c4 = 0; c4 < 16; ++c4) {
                float k0 = buf[(c4 * 4 + 0) * 64 + u];
                float k1 = buf[(c4 * 4 + 1) * 64 + u];
                float k2 = buf[(c4 * 4 + 2) * 64 + u];
                float k3 = buf[(c4 * 4 + 3) * 64 + u];
#pragma unroll
                for (int i = 0; i < 15; ++i) {
                    const float4 iv =
                        *(const float4*)&In[(tg * 15 + i + dt) * 128 + cbase + c4 * 4];
                    o[i] += iv.x * k0 + iv.y * k1 + iv.z * k2 + iv.w * k3;
                }
            }
        }
    }
#pragma unroll
    for (int i = 0; i < 15; ++i) {
        int t = tg * 15 + i;
        float v = o[i];
        float sp = fmaxf(v, 0.f) + log1pf(__expf(-fabsf(v)));
        out[((size_t)(b * 60 + t) * 400 + n) * 64 + u] = sp;
    }
}

// ---------------------------------------------------------------------------
extern "C" void kernel_launch(void* const* d_in, const int* in_sizes, int n_in,
                              void* d_out, int out_size, void* d_ws, size_t ws_size,
                              hipStream_t stream)
{
    const float* x    = (const float*)d_in[0];
    const float* A    = (const float*)d_in[1];
    const float* W1   = (const float*)d_in[2];
    const float* W2   = (const float*)d_in[3];
    const float* W3   = (const float*)d_in[4];
    const float* b1   = (const float*)d_in[5];
    const float* b2   = (const float*)d_in[6];
    const float* taW1 = (const float*)d_in[7];
    const float* taW2 = (const float*)d_in[8];
    const float* taW3 = (const float*)d_in[9];
    const float* Ve   = (const float*)d_in[10];
    const float* be   = (const float*)d_in[11];
    const float* tk   = (const float*)d_in[12];
    const float* tb   = (const float*)d_in[13];
    const float* rk   = (const float*)d_in[14];
    const float* rb   = (const float*)d_in[15];
    float* out = (float*)d_out;

    char* wsb = (char*)d_ws;
    size_t off = 0;
    auto alloc = [&](size_t bytes) -> void* {
        void* p = wsb + off;
        off += (bytes + 255) & ~(size_t)255;
        return p;
    };
    int*   row_cnt = (int*)alloc(400 * 4);
    int*   row_idx = (int*)alloc(400 * CAP * 4);
    int*   col_cnt = (int*)alloc(400 * 4);
    int*   col_idx = (int*)alloc(400 * CAP * 4);
    float* col_val = (float*)alloc(400 * CAP * 4);
    float* W2T     = (float*)alloc(25600 * 4);
    float* y       = (float*)alloc((size_t)12288000 * 4);
    float* r1      = (float*)alloc(480 * 64 * 4);
    float* rhs     = (float*)alloc(480 * 400 * 4);
    float* lhs     = (float*)alloc(480 * 400 * 4);
    float* Sbuf    = (float*)alloc(8 * 3600 * 4);
    float* ker     = (float*)alloc(8 * 3600 * 4);

    build_sparse<<<400, 64, 0, stream>>>(A, W1, W2, row_cnt, row_idx,
                                         col_cnt, col_idx, col_val, W2T);
    dgc_kernel<<<480, 256, 0, stream>>>(x, W2T, W3, b1, b2, row_cnt, row_idx,
                                        col_cnt, col_idx, col_val, y);
    ta_r1_rhs<<<480, 256, 0, stream>>>(y, taW1, taW3, r1, rhs);
    ta_lhs<<<480, 256, 0, stream>>>(r1, taW2, lhs);
    ta_product<<<dim3(15, 8), 256, 0, stream>>>(lhs, rhs, be, Sbuf);
    ta_softmax<<<8, 256, 0, stream>>>(Sbuf, Ve, ker);
    fused_conv<<<dim3(400, 8), 256, 0, stream>>>(y, ker, x, tk, tb, rk, rb, out);
}

// Round 2
// 1537.870 us; speedup vs baseline: 2.1366x; 2.1366x over previous
//
#include <hip/hip_runtime.h>
#include <hip/hip_bf16.h>

#define CAP 64   // max nnz per row/col of A (mean ~13, binomial(400,0.03)+diag)

typedef __attribute__((ext_vector_type(8))) short short8;   // 8 bf16 (4 VGPRs)
typedef __attribute__((ext_vector_type(4))) float f32x4;    // MFMA 16x16 acc

static __device__ __forceinline__ short f2b(float f) {
    union { float f; unsigned u; } v; v.f = f;
    unsigned r = v.u + 0x7FFFu + ((v.u >> 16) & 1u);   // RNE
    return (short)(r >> 16);
}

// ---------------------------------------------------------------------------
// Kernel 1: build sparse row/col lists of A, AW=A*W1 values (CSC), and W2^T.
// ---------------------------------------------------------------------------
__global__ __launch_bounds__(64) void build_sparse(
    const float* __restrict__ A, const float* __restrict__ W1,
    const float* __restrict__ W2,
    int* __restrict__ row_cnt, int* __restrict__ row_idx,
    int* __restrict__ col_cnt, int* __restrict__ col_idx,
    float* __restrict__ col_val, float* __restrict__ W2T)
{
    int m = blockIdx.x, lane = threadIdx.x;
    W2T[m * 64 + lane] = W2[lane * 400 + m];

    int base = 0;
    for (int c = 0; c < 400; c += 64) {
        int n = c + lane;
        float v = (n < 400) ? A[m * 400 + n] : 0.f;
        unsigned long long mk = __ballot(v != 0.f);
        int pre = __popcll(mk & ((1ull << lane) - 1ull));
        if (v != 0.f && base + pre < CAP) row_idx[m * CAP + base + pre] = n;
        base += __popcll(mk);
    }
    if (lane == 0) row_cnt[m] = base < CAP ? base : CAP;

    base = 0;
    for (int c = 0; c < 400; c += 64) {
        int n = c + lane;
        float v = (n < 400) ? A[n * 400 + m] : 0.f;
        unsigned long long mk = __ballot(v != 0.f);
        int pre = __popcll(mk & ((1ull << lane) - 1ull));
        if (v != 0.f && base + pre < CAP) {
            col_idx[m * CAP + base + pre] = n;
            col_val[m * CAP + base + pre] = v * W1[n * 400 + m];
        }
        base += __popcll(mk);
    }
    if (lane == 0) col_cnt[m] = base < CAP ? base : CAP;
}

// ---------------------------------------------------------------------------
// Kernel 2: DynamicGC -> y (B,T,N,64). (unchanged from R1 — R3 target)
// ---------------------------------------------------------------------------
__global__ __launch_bounds__(256) void dgc_kernel(
    const float* __restrict__ x, const float* __restrict__ W2T,
    const float* __restrict__ W3, const float* __restrict__ b1,
    const float* __restrict__ b2,
    const int* __restrict__ row_cnt, const int* __restrict__ row_idx,
    const int* __restrict__ col_cnt, const int* __restrict__ col_idx,
    const float* __restrict__ col_val,
    float* __restrict__ y)
{
    int bt = blockIdx.x;
    const float* xs = x + (size_t)bt * 25600;
    float* ys = y + (size_t)bt * 25600;
    int tid = threadIdx.x, lane = tid & 63, w = tid >> 6;

    float w3r[64];
#pragma unroll
    for (int f = 0; f < 64; ++f) w3r[f] = W3[f * 64 + lane];
    float b2v = b2[lane];

    for (int m = w; m < 400; m += 4) {
        int cc = col_cnt[m];
        float feat = 0.f;
        for (int l = 0; l < cc; ++l) {
            int n = col_idx[m * CAP + l];
            float wv = col_val[m * CAP + l];
            feat += wv * xs[(size_t)n * 64 + lane];
        }
        int rc = row_cnt[m];
        int lcl = lane < rc - 1 ? lane : rc - 1;
        int jj = row_idx[m * CAP + lcl];
        float d = b1[jj];
        const float4* w2r = (const float4*)(W2T + (size_t)jj * 64);
#pragma unroll
        for (int q = 0; q < 16; ++q) {
            float4 wv = w2r[q];
            d += __shfl(feat, 4 * q + 0) * wv.x + __shfl(feat, 4 * q + 1) * wv.y +
                 __shfl(feat, 4 * q + 2) * wv.z + __shfl(feat, 4 * q + 3) * wv.w;
        }
        float dv = (lane < rc) ? d : -1e30f;
        float mx = dv;
#pragma unroll
        for (int off = 32; off; off >>= 1) mx = fmaxf(mx, __shfl_xor(mx, off));
        float e = (lane < rc) ? __expf(dv - mx) : 0.f;
        float s = e;
#pragma unroll
        for (int off = 32; off; off >>= 1) s += __shfl_xor(s, off);
        float aval = e / s;
        float nf = 0.f;
        for (int l = 0; l < rc; ++l) {
            float av = __shfl(aval, l);
            int jv = __shfl(jj, l);
            nf += av * xs[(size_t)jv * 64 + lane];
        }
        float yv = b2v;
#pragma unroll
        for (int f = 0; f < 64; ++f) yv += __shfl(nf, f) * w3r[f];
        ys[(size_t)m * 64 + lane] = yv;
    }
}

// ---------------------------------------------------------------------------
// Kernel 3: r1[bt,f] = sum_n y[bt,n,f]*taW1[n];  rhs[bt,n] = sum_f y*taW3[f]
// ---------------------------------------------------------------------------
__global__ __launch_bounds__(256) void ta_r1_rhs(
    const float* __restrict__ y, const float* __restrict__ taW1,
    const float* __restrict__ taW3, float* __restrict__ r1,
    float* __restrict__ rhs)
{
    int bt = blockIdx.x;
    const float* ys = y + (size_t)bt * 25600;
    int tid = threadIdx.x, lane = tid & 63, w = tid >> 6;
    __shared__ __align__(16) float part[4][64];
    __shared__ __align__(16) float w3s[64];
    if (tid < 64) w3s[tid] = taW3[tid];
    float acc = 0.f;
    for (int n = w * 100; n < w * 100 + 100; ++n)
        acc += taW1[n] * ys[(size_t)n * 64 + lane];
    part[w][lane] = acc;
    __syncthreads();
    if (w == 0)
        r1[bt * 64 + lane] = part[0][lane] + part[1][lane] + part[2][lane] + part[3][lane];
    for (int n = tid; n < 400; n += 256) {
        const float4* yr = (const float4*)(ys + (size_t)n * 64);
        float a = 0.f;
#pragma unroll
        for (int q = 0; q < 16; ++q) {
            float4 v = yr[q];
            float4 wv = ((const float4*)w3s)[q];
            a += v.x * wv.x + v.y * wv.y + v.z * wv.z + v.w * wv.w;
        }
        rhs[bt * 400 + n] = a;
    }
}

// ---------------------------------------------------------------------------
// Kernel 4: lhs[bt,n] = sum_f r1[bt,f] * taW2[f,n]
// ---------------------------------------------------------------------------
__global__ __launch_bounds__(256) void ta_lhs(
    const float* __restrict__ r1, const float* __restrict__ taW2,
    float* __restrict__ lhs)
{
    int bt = blockIdx.x, tid = threadIdx.x;
    __shared__ float r1s[64];
    if (tid < 64) r1s[tid] = r1[bt * 64 + tid];
    __syncthreads();
    for (int n = tid; n < 400; n += 256) {
        float acc = 0.f;
#pragma unroll 8
        for (int f = 0; f < 64; ++f) acc += r1s[f] * taW2[f * 400 + n];
        lhs[bt * 400 + n] = acc;
    }
}

// ---------------------------------------------------------------------------
// Kernel 5: S[b,k,l] = sigmoid( lhs[b,k,:].rhs[b,l,:] + be[k,l] )
// ---------------------------------------------------------------------------
__global__ __launch_bounds__(256) void ta_product(
    const float* __restrict__ lhs, const float* __restrict__ rhs,
    const float* __restrict__ be, float* __restrict__ S)
{
    int kc = blockIdx.x, b = blockIdx.y, tid = threadIdx.x;
    if (tid >= 240) return;
    int k = kc * 4 + tid / 60;
    int l = tid % 60;
    const float4* lr = (const float4*)(lhs + (size_t)(b * 60 + k) * 400);
    const float4* rr = (const float4*)(rhs + (size_t)(b * 60 + l) * 400);
    float acc = 0.f;
    for (int q = 0; q < 100; ++q) {
        float4 a = lr[q], c = rr[q];
        acc += a.x * c.x + a.y * c.y + a.z * c.z + a.w * c.w;
    }
    float v = acc + be[k * 60 + l];
    S[b * 3600 + k * 60 + l] = 1.f / (1.f + __expf(-v));
}

// ---------------------------------------------------------------------------
// Kernel 6: E[b,j,l] = sum_k Ve[j,k]*S[b,k,l]; ker = softmax over j.
// ---------------------------------------------------------------------------
__global__ __launch_bounds__(256) void ta_softmax(
    const float* __restrict__ S, const float* __restrict__ Ve,
    float* __restrict__ ker)
{
    int b = blockIdx.x, tid = threadIdx.x;
    __shared__ float Ss[3600];
    __shared__ float Emat[3600];
    for (int i = tid; i < 3600; i += 256) Ss[i] = S[b * 3600 + i];
    __syncthreads();
    for (int p = tid; p < 3600; p += 256) {
        int j = p / 60, l = p % 60;
        float acc = 0.f;
        for (int k = 0; k < 60; ++k) acc += Ve[j * 60 + k] * Ss[k * 60 + l];
        Emat[p] = acc;
    }
    __syncthreads();
    for (int l = tid; l < 60; l += 256) {
        float mx = -1e30f;
        for (int j = 0; j < 60; ++j) mx = fmaxf(mx, Emat[j * 60 + l]);
        float s = 0.f;
        for (int j = 0; j < 60; ++j) s += __expf(Emat[j * 60 + l] - mx);
        float inv = 1.f / s;
        for (int j = 0; j < 60; ++j)
            ker[b * 3600 + j * 60 + l] = __expf(Emat[j * 60 + l] - mx) * inv;
    }
}

// ---------------------------------------------------------------------------
// Kernel 6.5: KT[u][dt*128+c] = bf16( c<64 ? tk[dt,0,c,u] : rk[dt,0,c-64,u] )
// 98304 elements; writes coalesced.
// ---------------------------------------------------------------------------
__global__ __launch_bounds__(256) void kt_prep(
    const float* __restrict__ tk, const float* __restrict__ rk,
    short* __restrict__ KT)
{
    int i = blockIdx.x * 256 + threadIdx.x;      // [0, 98304)
    int u = i / 1536, kk = i - u * 1536;
    int dt = kk >> 7, c = kk & 127;
    float v = (c < 64) ? tk[dt * 4096 + c * 64 + u]
                       : rk[dt * 4096 + (c - 64) * 64 + u];
    KT[i] = f2b(v);
}

// ---------------------------------------------------------------------------
// Kernel 7: fused time-mix + both temporal convs + softplus, bf16 MFMA.
// One block per (n, b), 4 waves. Wave w owns the 32x32 output quadrant
// (hm = w>>1 rows, hn = w&1 cols) as 2x2 MFMA 16x16 tiles.
//   time-mix GEMM: ta_out[t,u] = sum_s kerT[t,s] * ybT-as-B[s,u]   (K=64)
//   conv GEMM:     out[t,u]    = sum_{kk} In[t+dt, c] * KT[u, kk]  (K=1536)
// In: padded bf16 [75][136] (+8 pad -> 2-way banks); pad lo=5, hi=6 (SAME).
// B-fragments of the conv come straight from global KT (L2-resident).
// ---------------------------------------------------------------------------
__global__ __launch_bounds__(256) void fused_conv(
    const float* __restrict__ y, const float* __restrict__ ker,
    const float* __restrict__ x, const short* __restrict__ KT,
    const float* __restrict__ tb, const float* __restrict__ rb,
    float* __restrict__ out)
{
    int n = blockIdx.x, b = blockIdx.y;
    int tid = threadIdx.x, lane = tid & 63, w = tid >> 6;
    int m = lane & 15, quad = lane >> 4;
    int hm = w >> 1, hn = w & 1;

    __shared__ __align__(16) short In[75 * 136];    // 20400 B
    __shared__ __align__(16) short kerT[64 * 72];   // 9216 B, kerT[t][s]
    __shared__ __align__(16) short ybT[64 * 72];    // 9216 B, ybT[u][s]

    for (int i = tid; i < 75 * 136; i += 256) In[i] = 0;
    for (int i = tid; i < 64 * 72; i += 256) { kerT[i] = 0; ybT[i] = 0; }
    __syncthreads();

    // stage x -> In cols 64..127 (rows 5..64)
    for (int i = tid; i < 3840; i += 256) {
        int t = i >> 6, u = i & 63;
        In[(t + 5) * 136 + 64 + u] = f2b(x[((size_t)(b * 60 + t) * 400 + n) * 64 + u]);
    }
    // stage ybT[u][s] = y[b,s,n,u]
    for (int i = tid; i < 3840; i += 256) {
        int s = i >> 6, u = i & 63;
        ybT[u * 72 + s] = f2b(y[((size_t)(b * 60 + s) * 400 + n) * 64 + u]);
    }
    // stage kerT[t][s] = ker[b,s,t]
    for (int i = tid; i < 3600; i += 256) {
        int s = i / 60, t = i - s * 60;
        kerT[t * 72 + s] = f2b(ker[b * 3600 + s * 60 + t]);
    }
    __syncthreads();

    // ---- time-mix GEMM (M=64,N=64,K=64): 2 K-steps ----
    f32x4 tacc[2][2];
#pragma unroll
    for (int a = 0; a < 2; ++a)
#pragma unroll
        for (int c = 0; c < 2; ++c) tacc[a][c] = (f32x4){0.f, 0.f, 0.f, 0.f};
#pragma unroll
    for (int k0 = 0; k0 < 64; k0 += 32) {
        short8 afr[2], bfr[2];
#pragma unroll
        for (int mt = 0; mt < 2; ++mt)
            afr[mt] = *(const short8*)&kerT[(hm * 32 + mt * 16 + m) * 72 + k0 + quad * 8];
#pragma unroll
        for (int nt = 0; nt < 2; ++nt)
            bfr[nt] = *(const short8*)&ybT[(hn * 32 + nt * 16 + m) * 72 + k0 + quad * 8];
#pragma unroll
        for (int mt = 0; mt < 2; ++mt)
#pragma unroll
            for (int nt = 0; nt < 2; ++nt)
                tacc[mt][nt] = __builtin_amdgcn_mfma_f32_16x16x32_bf16(
                    afr[mt], bfr[nt], tacc[mt][nt], 0, 0, 0);
    }
    __syncthreads();   // all ybT/kerT reads done before In cols 0..63 written

    // write ta_out -> In cols 0..63 (rows 5..64 only; padded t>=60 stays 0)
#pragma unroll
    for (int mt = 0; mt < 2; ++mt)
#pragma unroll
        for (int nt = 0; nt < 2; ++nt)
#pragma unroll
            for (int r = 0; r < 4; ++r) {
                int t = hm * 32 + mt * 16 + quad * 4 + r;
                int u = hn * 32 + nt * 16 + m;
                if (t < 60) In[(t + 5) * 136 + u] = f2b(tacc[mt][nt][r]);
            }
    __syncthreads();

    // ---- conv GEMM (M=64,N=64,K=1536): A from LDS, B from global KT ----
    f32x4 acc[2][2];
#pragma unroll
    for (int a = 0; a < 2; ++a)
#pragma unroll
        for (int c = 0; c < 2; ++c) acc[a][c] = (f32x4){0.f, 0.f, 0.f, 0.f};

    const short* kt0 = KT + (size_t)(hn * 32 + m) * 1536 + quad * 8;
    const short* kt1 = KT + (size_t)(hn * 32 + 16 + m) * 1536 + quad * 8;

#pragma unroll 4
    for (int kk = 0; kk < 1536; kk += 32) {
        int dt = kk >> 7, c0 = (kk & 127) + quad * 8;
        short8 a0 = *(const short8*)&In[(hm * 32 + m + dt) * 136 + c0];
        short8 a1 = *(const short8*)&In[(hm * 32 + 16 + m + dt) * 136 + c0];
        short8 b0 = *(const short8*)(kt0 + kk);
        short8 b1 = *(const short8*)(kt1 + kk);
        acc[0][0] = __builtin_amdgcn_mfma_f32_16x16x32_bf16(a0, b0, acc[0][0], 0, 0, 0);
        acc[0][1] = __builtin_amdgcn_mfma_f32_16x16x32_bf16(a0, b1, acc[0][1], 0, 0, 0);
        acc[1][0] = __builtin_amdgcn_mfma_f32_16x16x32_bf16(a1, b0, acc[1][0], 0, 0, 0);
        acc[1][1] = __builtin_amdgcn_mfma_f32_16x16x32_bf16(a1, b1, acc[1][1], 0, 0, 0);
    }

    // ---- epilogue: bias + softplus + store (t<60) ----
    float bias[2];
#pragma unroll
    for (int nt = 0; nt < 2; ++nt) {
        int u = hn * 32 + nt * 16 + m;
        bias[nt] = tb[u] + rb[u];
    }
#pragma unroll
    for (int mt = 0; mt < 2; ++mt)
#pragma unroll
        for (int r = 0; r < 4; ++r) {
            int t = hm * 32 + mt * 16 + quad * 4 + r;
            if (t >= 60) continue;
#pragma unroll
            for (int nt = 0; nt < 2; ++nt) {
                int u = hn * 32 + nt * 16 + m;
                float v = acc[mt][nt][r] + bias[nt];
                float sp = fmaxf(v, 0.f) + log1pf(__expf(-fabsf(v)));
                out[((size_t)(b * 60 + t) * 400 + n) * 64 + u] = sp;
            }
        }
}

// ---------------------------------------------------------------------------
extern "C" void kernel_launch(void* const* d_in, const int* in_sizes, int n_in,
                              void* d_out, int out_size, void* d_ws, size_t ws_size,
                              hipStream_t stream)
{
    const float* x    = (const float*)d_in[0];
    const float* A    = (const float*)d_in[1];
    const float* W1   = (const float*)d_in[2];
    const float* W2   = (const float*)d_in[3];
    const float* W3   = (const float*)d_in[4];
    const float* b1   = (const float*)d_in[5];
    const float* b2   = (const float*)d_in[6];
    const float* taW1 = (const float*)d_in[7];
    const float* taW2 = (const float*)d_in[8];
    const float* taW3 = (const float*)d_in[9];
    const float* Ve   = (const float*)d_in[10];
    const float* be   = (const float*)d_in[11];
    const float* tk   = (const float*)d_in[12];
    const float* tb   = (const float*)d_in[13];
    const float* rk   = (const float*)d_in[14];
    const float* rb   = (const float*)d_in[15];
    float* out = (float*)d_out;

    char* wsb = (char*)d_ws;
    size_t off = 0;
    auto alloc = [&](size_t bytes) -> void* {
        void* p = wsb + off;
        off += (bytes + 255) & ~(size_t)255;
        return p;
    };
    int*   row_cnt = (int*)alloc(400 * 4);
    int*   row_idx = (int*)alloc(400 * CAP * 4);
    int*   col_cnt = (int*)alloc(400 * 4);
    int*   col_idx = (int*)alloc(400 * CAP * 4);
    float* col_val = (float*)alloc(400 * CAP * 4);
    float* W2T     = (float*)alloc(25600 * 4);
    float* y       = (float*)alloc((size_t)12288000 * 4);
    float* r1      = (float*)alloc(480 * 64 * 4);
    float* rhs     = (float*)alloc(480 * 400 * 4);
    float* lhs     = (float*)alloc(480 * 400 * 4);
    float* Sbuf    = (float*)alloc(8 * 3600 * 4);
    float* ker     = (float*)alloc(8 * 3600 * 4);
    short* KT      = (short*)alloc((size_t)64 * 1536 * 2);

    build_sparse<<<400, 64, 0, stream>>>(A, W1, W2, row_cnt, row_idx,
                                         col_cnt, col_idx, col_val, W2T);
    dgc_kernel<<<480, 256, 0, stream>>>(x, W2T, W3, b1, b2, row_cnt, row_idx,
                                        col_cnt, col_idx, col_val, y);
    ta_r1_rhs<<<480, 256, 0, stream>>>(y, taW1, taW3, r1, rhs);
    ta_lhs<<<480, 256, 0, stream>>>(r1, taW2, lhs);
    ta_product<<<dim3(15, 8), 256, 0, stream>>>(lhs, rhs, be, Sbuf);
    ta_softmax<<<8, 256, 0, stream>>>(Sbuf, Ve, ker);
    kt_prep<<<384, 256, 0, stream>>>(tk, rk, KT);
    fused_conv<<<dim3(400, 8), 256, 0, stream>>>(y, ker, x, KT, tb, rb, out);
}

// Round 3
// 648.763 us; speedup vs baseline: 5.0647x; 2.3705x over previous
//
#include <hip/hip_runtime.h>
#include <hip/hip_bf16.h>

typedef __attribute__((ext_vector_type(8))) short short8;   // 8 bf16 (4 VGPRs)
typedef __attribute__((ext_vector_type(4))) float f32x4;    // MFMA 16x16 acc

static __device__ __forceinline__ short f2b(float f) {
    union { float f; unsigned u; } v; v.f = f;
    unsigned r = v.u + 0x7FFFu + ((v.u >> 16) & 1u);   // RNE
    return (short)(r >> 16);
}

// ---------------------------------------------------------------------------
// prep_w: AWT[448][416] bf16 (AWT[m][n] = A[n][m]*W1[n][m], zero-padded),
//         W2Tb[400][64] bf16 (= W2[f][j] transposed), W3Tb[64][64] bf16.
// grid: 844 x 256 = 216064 = 186368 + 25600 + 4096
// ---------------------------------------------------------------------------
__global__ __launch_bounds__(256) void prep_w(
    const float* __restrict__ A, const float* __restrict__ W1,
    const float* __restrict__ W2, const float* __restrict__ W3,
    short* __restrict__ AWT, short* __restrict__ W2Tb, short* __restrict__ W3Tb)
{
    int i = blockIdx.x * 256 + threadIdx.x;
    if (i < 186368) {
        int m = i / 416, n = i - m * 416;
        AWT[i] = (m < 400 && n < 400) ? f2b(A[n * 400 + m] * W1[n * 400 + m])
                                      : (short)0;
    } else if (i < 186368 + 25600) {
        int i2 = i - 186368;
        int j = i2 >> 6, f = i2 & 63;
        W2Tb[i2] = f2b(W2[f * 400 + j]);
    } else {
        int i3 = i - 186368 - 25600;
        int u = i3 >> 6, f = i3 & 63;
        W3Tb[i3] = f2b(W3[f * 64 + u]);
    }
}

// ---------------------------------------------------------------------------
// prep_xt: xTb[bt][f=64][n stride 416] bf16 = transpose of x[bt][n][f],
// cols 400..415 zeroed. One block per bt; LDS tile transpose (pad 65).
// ---------------------------------------------------------------------------
__global__ __launch_bounds__(256) void prep_xt(
    const float* __restrict__ x, short* __restrict__ xTb)
{
    int bt = blockIdx.x, tid = threadIdx.x;
    __shared__ float tile[64][65];
    const float* xs = x + (size_t)bt * 25600;
    short* xo = xTb + (size_t)bt * 64 * 416;
    for (int c = 0; c < 7; ++c) {
        int n0 = c * 64, cnt = (c == 6) ? 16 : 64;
        __syncthreads();
        for (int i = tid; i < cnt * 64; i += 256) {
            int r = i >> 6, f = i & 63;
            tile[r][f] = xs[(size_t)(n0 + r) * 64 + f];
        }
        __syncthreads();
        for (int i = tid; i < cnt * 64; i += 256) {
            int r = i & (cnt - 1), f = i / cnt;
            xo[(size_t)f * 416 + n0 + r] = f2b(tile[r][f]);
        }
    }
    for (int i = tid; i < 64 * 16; i += 256) {
        int f = i >> 4, n = 400 + (i & 15);
        xo[(size_t)f * 416 + n] = 0;
    }
}

// ---------------------------------------------------------------------------
// dgc_mfma: fused DynamicGC, all-MFMA. grid (480 bt, 7 m-tiles), 4 waves.
// Wave w owns m-rows [mt*64 + w*16, +16).
//   A: feat = AWT @ x          (K=416, B-frags from global xTb)
//   B: dense = feat @ W2 + b1, mask by A, softmax over j (in-register)
//   D: nodef = attn @ x        (K=416, A-frags from LDS attn)
//   E: y = nodef @ W3 + b2
// LDS: attnS 64x424 bf16 (54272 B) + featS 64x72 bf16 (9216 B) = 63488 B.
// ---------------------------------------------------------------------------
__global__ __launch_bounds__(256) void dgc_mfma(
    const float* __restrict__ Ap, const float* __restrict__ b1p,
    const float* __restrict__ b2p,
    const short* __restrict__ AWT, const short* __restrict__ W2Tb,
    const short* __restrict__ W3Tb, const short* __restrict__ xTb,
    float* __restrict__ y)
{
    int bt = blockIdx.x, mt = blockIdx.y;
    int tid = threadIdx.x, lane = tid & 63, w = tid >> 6;
    int lm = lane & 15, quad = lane >> 4;

    __shared__ __align__(16) short attnS[64 * 424];
    __shared__ __align__(16) short featS[64 * 72];

    // zero attn pad cols 400..423 (K-loop reads through col 415)
    for (int i = tid; i < 64 * 24; i += 256) {
        int r = i / 24, c = i - r * 24;
        attnS[r * 424 + 400 + c] = 0;
    }

    const short* xt = xTb + (size_t)bt * 64 * 416;

    // ---- Phase A: feat stripe [16 x 64] ----
    f32x4 fa[4];
#pragma unroll
    for (int i = 0; i < 4; ++i) fa[i] = (f32x4){0.f, 0.f, 0.f, 0.f};
    const short* awt_row = AWT + (size_t)(mt * 64 + w * 16 + lm) * 416 + quad * 8;
#pragma unroll
    for (int k0 = 0; k0 < 416; k0 += 32) {
        short8 af = *(const short8*)(awt_row + k0);
#pragma unroll
        for (int ft = 0; ft < 4; ++ft) {
            short8 bf = *(const short8*)(xt + (size_t)(ft * 16 + lm) * 416 + k0 + quad * 8);
            fa[ft] = __builtin_amdgcn_mfma_f32_16x16x32_bf16(af, bf, fa[ft], 0, 0, 0);
        }
    }
#pragma unroll
    for (int ft = 0; ft < 4; ++ft)
#pragma unroll
        for (int r = 0; r < 4; ++r)
            featS[(w * 16 + quad * 4 + r) * 72 + ft * 16 + lm] = f2b(fa[ft][r]);
    __syncthreads();

    // ---- Phase B: dense stripe [16 x 400], mask, softmax ----
    f32x4 da[25];
#pragma unroll
    for (int jt = 0; jt < 25; ++jt) da[jt] = (f32x4){0.f, 0.f, 0.f, 0.f};
    short8 a0 = *(const short8*)&featS[(w * 16 + lm) * 72 + quad * 8];
    short8 a1 = *(const short8*)&featS[(w * 16 + lm) * 72 + 32 + quad * 8];
#pragma unroll
    for (int jt = 0; jt < 25; ++jt) {
        short8 bf0 = *(const short8*)(W2Tb + (size_t)(jt * 16 + lm) * 64 + quad * 8);
        short8 bf1 = *(const short8*)(W2Tb + (size_t)(jt * 16 + lm) * 64 + 32 + quad * 8);
        da[jt] = __builtin_amdgcn_mfma_f32_16x16x32_bf16(a0, bf0, da[jt], 0, 0, 0);
        da[jt] = __builtin_amdgcn_mfma_f32_16x16x32_bf16(a1, bf1, da[jt], 0, 0, 0);
    }
    int mrb = mt * 64 + w * 16 + quad * 4;
#pragma unroll
    for (int jt = 0; jt < 25; ++jt) {
        int j = jt * 16 + lm;
        float b1v = b1p[j];
#pragma unroll
        for (int r = 0; r < 4; ++r) {
            int mr = mrb + r; if (mr > 399) mr = 399;
            float av = Ap[(size_t)mr * 400 + j];
            da[jt][r] = (av != 0.f) ? (da[jt][r] + b1v) : -1e30f;
        }
    }
    float inv_s[4];
#pragma unroll
    for (int r = 0; r < 4; ++r) {
        float mx = -1e30f;
#pragma unroll
        for (int jt = 0; jt < 25; ++jt) mx = fmaxf(mx, da[jt][r]);
        mx = fmaxf(mx, __shfl_xor(mx, 1));
        mx = fmaxf(mx, __shfl_xor(mx, 2));
        mx = fmaxf(mx, __shfl_xor(mx, 4));
        mx = fmaxf(mx, __shfl_xor(mx, 8));
        float s = 0.f;
#pragma unroll
        for (int jt = 0; jt < 25; ++jt) {
            float d = da[jt][r];
            float e = (d > -1e29f) ? __expf(d - mx) : 0.f;
            da[jt][r] = e;
            s += e;
        }
        s += __shfl_xor(s, 1);
        s += __shfl_xor(s, 2);
        s += __shfl_xor(s, 4);
        s += __shfl_xor(s, 8);
        inv_s[r] = 1.f / s;
    }
#pragma unroll
    for (int jt = 0; jt < 25; ++jt)
#pragma unroll
        for (int r = 0; r < 4; ++r)
            attnS[(w * 16 + quad * 4 + r) * 424 + jt * 16 + lm] = f2b(da[jt][r] * inv_s[r]);
    __syncthreads();

    // ---- Phase D: nodef stripe [16 x 64] = attn @ x ----
    f32x4 na[4];
#pragma unroll
    for (int i = 0; i < 4; ++i) na[i] = (f32x4){0.f, 0.f, 0.f, 0.f};
    const short* at_row = &attnS[(w * 16 + lm) * 424 + quad * 8];
#pragma unroll
    for (int k0 = 0; k0 < 416; k0 += 32) {
        short8 af = *(const short8*)(at_row + k0);
#pragma unroll
        for (int ft = 0; ft < 4; ++ft) {
            short8 bf = *(const short8*)(xt + (size_t)(ft * 16 + lm) * 416 + k0 + quad * 8);
            na[ft] = __builtin_amdgcn_mfma_f32_16x16x32_bf16(af, bf, na[ft], 0, 0, 0);
        }
    }
    __syncthreads();   // featS reads (phase B) complete before overwrite
#pragma unroll
    for (int ft = 0; ft < 4; ++ft)
#pragma unroll
        for (int r = 0; r < 4; ++r)
            featS[(w * 16 + quad * 4 + r) * 72 + ft * 16 + lm] = f2b(na[ft][r]);
    __syncthreads();

    // ---- Phase E: y stripe [16 x 64] = nodef @ W3 + b2 ----
    f32x4 ya[4];
#pragma unroll
    for (int i = 0; i < 4; ++i) ya[i] = (f32x4){0.f, 0.f, 0.f, 0.f};
    short8 n0 = *(const short8*)&featS[(w * 16 + lm) * 72 + quad * 8];
    short8 n1 = *(const short8*)&featS[(w * 16 + lm) * 72 + 32 + quad * 8];
#pragma unroll
    for (int ut = 0; ut < 4; ++ut) {
        short8 bf0 = *(const short8*)(W3Tb + (size_t)(ut * 16 + lm) * 64 + quad * 8);
        short8 bf1 = *(const short8*)(W3Tb + (size_t)(ut * 16 + lm) * 64 + 32 + quad * 8);
        ya[ut] = __builtin_amdgcn_mfma_f32_16x16x32_bf16(n0, bf0, ya[ut], 0, 0, 0);
        ya[ut] = __builtin_amdgcn_mfma_f32_16x16x32_bf16(n1, bf1, ya[ut], 0, 0, 0);
    }
#pragma unroll
    for (int ut = 0; ut < 4; ++ut) {
        int u = ut * 16 + lm;
        float b2v = b2p[u];
#pragma unroll
        for (int r = 0; r < 4; ++r) {
            int mrow = mrb + r;
            if (mrow < 400)
                y[((size_t)bt * 400 + mrow) * 64 + u] = ya[ut][r] + b2v;
        }
    }
}

// ---------------------------------------------------------------------------
// Kernel 3: r1[bt,f] = sum_n y[bt,n,f]*taW1[n];  rhs[bt,n] = sum_f y*taW3[f]
// ---------------------------------------------------------------------------
__global__ __launch_bounds__(256) void ta_r1_rhs(
    const float* __restrict__ y, const float* __restrict__ taW1,
    const float* __restrict__ taW3, float* __restrict__ r1,
    float* __restrict__ rhs)
{
    int bt = blockIdx.x;
    const float* ys = y + (size_t)bt * 25600;
    int tid = threadIdx.x, lane = tid & 63, w = tid >> 6;
    __shared__ __align__(16) float part[4][64];
    __shared__ __align__(16) float w3s[64];
    if (tid < 64) w3s[tid] = taW3[tid];
    float acc = 0.f;
    for (int n = w * 100; n < w * 100 + 100; ++n)
        acc += taW1[n] * ys[(size_t)n * 64 + lane];
    part[w][lane] = acc;
    __syncthreads();
    if (w == 0)
        r1[bt * 64 + lane] = part[0][lane] + part[1][lane] + part[2][lane] + part[3][lane];
    for (int n = tid; n < 400; n += 256) {
        const float4* yr = (const float4*)(ys + (size_t)n * 64);
        float a = 0.f;
#pragma unroll
        for (int q = 0; q < 16; ++q) {
            float4 v = yr[q];
            float4 wv = ((const float4*)w3s)[q];
            a += v.x * wv.x + v.y * wv.y + v.z * wv.z + v.w * wv.w;
        }
        rhs[bt * 400 + n] = a;
    }
}

// ---------------------------------------------------------------------------
// Kernel 4: lhs[bt,n] = sum_f r1[bt,f] * taW2[f,n]
// ---------------------------------------------------------------------------
__global__ __launch_bounds__(256) void ta_lhs(
    const float* __restrict__ r1, const float* __restrict__ taW2,
    float* __restrict__ lhs)
{
    int bt = blockIdx.x, tid = threadIdx.x;
    __shared__ float r1s[64];
    if (tid < 64) r1s[tid] = r1[bt * 64 + tid];
    __syncthreads();
    for (int n = tid; n < 400; n += 256) {
        float acc = 0.f;
#pragma unroll 8
        for (int f = 0; f < 64; ++f) acc += r1s[f] * taW2[f * 400 + n];
        lhs[bt * 400 + n] = acc;
    }
}

// ---------------------------------------------------------------------------
// Kernel 5: S[b,k,l] = sigmoid( lhs[b,k,:].rhs[b,l,:] + be[k,l] )
// ---------------------------------------------------------------------------
__global__ __launch_bounds__(256) void ta_product(
    const float* __restrict__ lhs, const float* __restrict__ rhs,
    const float* __restrict__ be, float* __restrict__ S)
{
    int kc = blockIdx.x, b = blockIdx.y, tid = threadIdx.x;
    if (tid >= 240) return;
    int k = kc * 4 + tid / 60;
    int l = tid % 60;
    const float4* lr = (const float4*)(lhs + (size_t)(b * 60 + k) * 400);
    const float4* rr = (const float4*)(rhs + (size_t)(b * 60 + l) * 400);
    float acc = 0.f;
    for (int q = 0; q < 100; ++q) {
        float4 a = lr[q], c = rr[q];
        acc += a.x * c.x + a.y * c.y + a.z * c.z + a.w * c.w;
    }
    float v = acc + be[k * 60 + l];
    S[b * 3600 + k * 60 + l] = 1.f / (1.f + __expf(-v));
}

// ---------------------------------------------------------------------------
// Kernel 6: E[b,j,l] = sum_k Ve[j,k]*S[b,k,l]; ker = softmax over j.
// ---------------------------------------------------------------------------
__global__ __launch_bounds__(256) void ta_softmax(
    const float* __restrict__ S, const float* __restrict__ Ve,
    float* __restrict__ ker)
{
    int b = blockIdx.x, tid = threadIdx.x;
    __shared__ float Ss[3600];
    __shared__ float Emat[3600];
    for (int i = tid; i < 3600; i += 256) Ss[i] = S[b * 3600 + i];
    __syncthreads();
    for (int p = tid; p < 3600; p += 256) {
        int j = p / 60, l = p % 60;
        float acc = 0.f;
        for (int k = 0; k < 60; ++k) acc += Ve[j * 60 + k] * Ss[k * 60 + l];
        Emat[p] = acc;
    }
    __syncthreads();
    for (int l = tid; l < 60; l += 256) {
        float mx = -1e30f;
        for (int j = 0; j < 60; ++j) mx = fmaxf(mx, Emat[j * 60 + l]);
        float s = 0.f;
        for (int j = 0; j < 60; ++j) s += __expf(Emat[j * 60 + l] - mx);
        float inv = 1.f / s;
        for (int j = 0; j < 60; ++j)
            ker[b * 3600 + j * 60 + l] = __expf(Emat[j * 60 + l] - mx) * inv;
    }
}

// ---------------------------------------------------------------------------
// kt_prep: KT[u][dt*128+c] = bf16( c<64 ? tk[dt,0,c,u] : rk[dt,0,c-64,u] )
// ---------------------------------------------------------------------------
__global__ __launch_bounds__(256) void kt_prep(
    const float* __restrict__ tk, const float* __restrict__ rk,
    short* __restrict__ KT)
{
    int i = blockIdx.x * 256 + threadIdx.x;      // [0, 98304)
    int u = i / 1536, kk = i - u * 1536;
    int dt = kk >> 7, c = kk & 127;
    float v = (c < 64) ? tk[dt * 4096 + c * 64 + u]
                       : rk[dt * 4096 + (c - 64) * 64 + u];
    KT[i] = f2b(v);
}

// ---------------------------------------------------------------------------
// fused_conv: time-mix + both temporal convs + softplus, bf16 MFMA.
// (unchanged from R2)
// ---------------------------------------------------------------------------
__global__ __launch_bounds__(256) void fused_conv(
    const float* __restrict__ y, const float* __restrict__ ker,
    const float* __restrict__ x, const short* __restrict__ KT,
    const float* __restrict__ tb, const float* __restrict__ rb,
    float* __restrict__ out)
{
    int n = blockIdx.x, b = blockIdx.y;
    int tid = threadIdx.x, lane = tid & 63, w = tid >> 6;
    int m = lane & 15, quad = lane >> 4;
    int hm = w >> 1, hn = w & 1;

    __shared__ __align__(16) short In[75 * 136];
    __shared__ __align__(16) short kerT[64 * 72];
    __shared__ __align__(16) short ybT[64 * 72];

    for (int i = tid; i < 75 * 136; i += 256) In[i] = 0;
    for (int i = tid; i < 64 * 72; i += 256) { kerT[i] = 0; ybT[i] = 0; }
    __syncthreads();

    for (int i = tid; i < 3840; i += 256) {
        int t = i >> 6, u = i & 63;
        In[(t + 5) * 136 + 64 + u] = f2b(x[((size_t)(b * 60 + t) * 400 + n) * 64 + u]);
    }
    for (int i = tid; i < 3840; i += 256) {
        int s = i >> 6, u = i & 63;
        ybT[u * 72 + s] = f2b(y[((size_t)(b * 60 + s) * 400 + n) * 64 + u]);
    }
    for (int i = tid; i < 3600; i += 256) {
        int s = i / 60, t = i - s * 60;
        kerT[t * 72 + s] = f2b(ker[b * 3600 + s * 60 + t]);
    }
    __syncthreads();

    f32x4 tacc[2][2];
#pragma unroll
    for (int a = 0; a < 2; ++a)
#pragma unroll
        for (int c = 0; c < 2; ++c) tacc[a][c] = (f32x4){0.f, 0.f, 0.f, 0.f};
#pragma unroll
    for (int k0 = 0; k0 < 64; k0 += 32) {
        short8 afr[2], bfr[2];
#pragma unroll
        for (int mt = 0; mt < 2; ++mt)
            afr[mt] = *(const short8*)&kerT[(hm * 32 + mt * 16 + m) * 72 + k0 + quad * 8];
#pragma unroll
        for (int nt = 0; nt < 2; ++nt)
            bfr[nt] = *(const short8*)&ybT[(hn * 32 + nt * 16 + m) * 72 + k0 + quad * 8];
#pragma unroll
        for (int mt = 0; mt < 2; ++mt)
#pragma unroll
            for (int nt = 0; nt < 2; ++nt)
                tacc[mt][nt] = __builtin_amdgcn_mfma_f32_16x16x32_bf16(
                    afr[mt], bfr[nt], tacc[mt][nt], 0, 0, 0);
    }
    __syncthreads();

#pragma unroll
    for (int mt = 0; mt < 2; ++mt)
#pragma unroll
        for (int nt = 0; nt < 2; ++nt)
#pragma unroll
            for (int r = 0; r < 4; ++r) {
                int t = hm * 32 + mt * 16 + quad * 4 + r;
                int u = hn * 32 + nt * 16 + m;
                if (t < 60) In[(t + 5) * 136 + u] = f2b(tacc[mt][nt][r]);
            }
    __syncthreads();

    f32x4 acc[2][2];
#pragma unroll
    for (int a = 0; a < 2; ++a)
#pragma unroll
        for (int c = 0; c < 2; ++c) acc[a][c] = (f32x4){0.f, 0.f, 0.f, 0.f};

    const short* kt0 = KT + (size_t)(hn * 32 + m) * 1536 + quad * 8;
    const short* kt1 = KT + (size_t)(hn * 32 + 16 + m) * 1536 + quad * 8;

#pragma unroll 4
    for (int kk = 0; kk < 1536; kk += 32) {
        int dt = kk >> 7, c0 = (kk & 127) + quad * 8;
        short8 a0 = *(const short8*)&In[(hm * 32 + m + dt) * 136 + c0];
        short8 a1 = *(const short8*)&In[(hm * 32 + 16 + m + dt) * 136 + c0];
        short8 b0 = *(const short8*)(kt0 + kk);
        short8 b1 = *(const short8*)(kt1 + kk);
        acc[0][0] = __builtin_amdgcn_mfma_f32_16x16x32_bf16(a0, b0, acc[0][0], 0, 0, 0);
        acc[0][1] = __builtin_amdgcn_mfma_f32_16x16x32_bf16(a0, b1, acc[0][1], 0, 0, 0);
        acc[1][0] = __builtin_amdgcn_mfma_f32_16x16x32_bf16(a1, b0, acc[1][0], 0, 0, 0);
        acc[1][1] = __builtin_amdgcn_mfma_f32_16x16x32_bf16(a1, b1, acc[1][1], 0, 0, 0);
    }

    float bias[2];
#pragma unroll
    for (int nt = 0; nt < 2; ++nt) {
        int u = hn * 32 + nt * 16 + m;
        bias[nt] = tb[u] + rb[u];
    }
#pragma unroll
    for (int mt = 0; mt < 2; ++mt)
#pragma unroll
        for (int r = 0; r < 4; ++r) {
            int t = hm * 32 + mt * 16 + quad * 4 + r;
            if (t >= 60) continue;
#pragma unroll
            for (int nt = 0; nt < 2; ++nt) {
                int u = hn * 32 + nt * 16 + m;
                float v = acc[mt][nt][r] + bias[nt];
                float sp = fmaxf(v, 0.f) + log1pf(__expf(-fabsf(v)));
                out[((size_t)(b * 60 + t) * 400 + n) * 64 + u] = sp;
            }
        }
}

// ---------------------------------------------------------------------------
extern "C" void kernel_launch(void* const* d_in, const int* in_sizes, int n_in,
                              void* d_out, int out_size, void* d_ws, size_t ws_size,
                              hipStream_t stream)
{
    const float* x    = (const float*)d_in[0];
    const float* A    = (const float*)d_in[1];
    const float* W1   = (const float*)d_in[2];
    const float* W2   = (const float*)d_in[3];
    const float* W3   = (const float*)d_in[4];
    const float* b1   = (const float*)d_in[5];
    const float* b2   = (const float*)d_in[6];
    const float* taW1 = (const float*)d_in[7];
    const float* taW2 = (const float*)d_in[8];
    const float* taW3 = (const float*)d_in[9];
    const float* Ve   = (const float*)d_in[10];
    const float* be   = (const float*)d_in[11];
    const float* tk   = (const float*)d_in[12];
    const float* tb   = (const float*)d_in[13];
    const float* rk   = (const float*)d_in[14];
    const float* rb   = (const float*)d_in[15];
    float* out = (float*)d_out;

    char* wsb = (char*)d_ws;
    size_t off = 0;
    auto alloc = [&](size_t bytes) -> void* {
        void* p = wsb + off;
        off += (bytes + 255) & ~(size_t)255;
        return p;
    };
    short* AWT   = (short*)alloc((size_t)448 * 416 * 2);
    short* W2Tb  = (short*)alloc((size_t)400 * 64 * 2);
    short* W3Tb  = (short*)alloc((size_t)64 * 64 * 2);
    short* xTb   = (short*)alloc((size_t)480 * 64 * 416 * 2);
    float* y     = (float*)alloc((size_t)12288000 * 4);
    float* r1    = (float*)alloc(480 * 64 * 4);
    float* rhs   = (float*)alloc(480 * 400 * 4);
    float* lhs   = (float*)alloc(480 * 400 * 4);
    float* Sbuf  = (float*)alloc(8 * 3600 * 4);
    float* ker   = (float*)alloc(8 * 3600 * 4);
    short* KT    = (short*)alloc((size_t)64 * 1536 * 2);

    prep_w<<<844, 256, 0, stream>>>(A, W1, W2, W3, AWT, W2Tb, W3Tb);
    prep_xt<<<480, 256, 0, stream>>>(x, xTb);
    dgc_mfma<<<dim3(480, 7), 256, 0, stream>>>(A, b1, b2, AWT, W2Tb, W3Tb, xTb, y);
    ta_r1_rhs<<<480, 256, 0, stream>>>(y, taW1, taW3, r1, rhs);
    ta_lhs<<<480, 256, 0, stream>>>(r1, taW2, lhs);
    ta_product<<<dim3(15, 8), 256, 0, stream>>>(lhs, rhs, be, Sbuf);
    ta_softmax<<<8, 256, 0, stream>>>(Sbuf, Ve, ker);
    kt_prep<<<384, 256, 0, stream>>>(tk, rk, KT);
    fused_conv<<<dim3(400, 8), 256, 0, stream>>>(y, ker, x, KT, tb, rb, out);
}